// Round 3
// baseline (52.780 us; speedup 1.0000x reference)
//
#include <hip/hip_runtime.h>
#include <math.h>

#define EPS 1e-6f

// Input: feat_map [T=32][D=256][H=56][W=56] fp32 (d-slice = 3136 floats = 12.25 KB)
//
// loc_reduce: grid = 32 t * 16 d-groups = 512 blocks (2/CU), 832 threads (784 active).
//   Each block streams a contiguous 16-d-slice chunk (196 KB). Thread tid<784 has a
//   FIXED (h = tid/14, w-group v = tid%14) slice position; loops over its 16 d's in
//   2 batches of 8 BATCHED loads (8 outstanding per wave) with register accumulation.
//   Epilogue: LDS-atomic reduce to 4x56 partials, disjoint ws stores (no atomics, no memset).
//
// ws partials layout: [block=(t*16+dg)][arr(0:s1h,1:s2h,2:s1w,3:s2w)][56]  (114688 floats)
// out layout: [0]=tot, then log10(ga1)[32*56], ga2, ga3, ga4.

__global__ __launch_bounds__(832, 7) void loc_reduce(const float* __restrict__ f,
                                                     float* __restrict__ ws) {
    const int t   = blockIdx.x >> 4;
    const int dg  = blockIdx.x & 15;
    const int tid = threadIdx.x;

    __shared__ float ls[224];  // [arr][56]
    for (int k = tid; k < 224; k += 832) ls[k] = 0.f;
    __syncthreads();

    if (tid < 784) {
        const int h = tid / 14;
        const int v = tid % 14;
        const float4* p4 = reinterpret_cast<const float4*>(
            f + (size_t)t * 802816 + (size_t)(dg * 16) * 3136) + (size_t)h * 14 + v;

        float s10 = 0.f, s11 = 0.f, s12 = 0.f, s13 = 0.f;
        float s20 = 0.f, s21 = 0.f, s22 = 0.f, s23 = 0.f;

        #pragma unroll
        for (int b = 0; b < 2; ++b) {
            float4 x[8];
            #pragma unroll
            for (int u = 0; u < 8; ++u)
                x[u] = p4[(size_t)(b * 8 + u) * 784];
            #pragma unroll
            for (int u = 0; u < 8; ++u) {
                s10 += x[u].x; s11 += x[u].y; s12 += x[u].z; s13 += x[u].w;
                s20 += x[u].x * x[u].x; s21 += x[u].y * x[u].y;
                s22 += x[u].z * x[u].z; s23 += x[u].w * x[u].w;
            }
        }

        // per-h sums (same-address contention, epilogue-only)
        atomicAdd(&ls[0 * 56 + h], s10 + s11 + s12 + s13);
        atomicAdd(&ls[1 * 56 + h], s20 + s21 + s22 + s23);
        // per-w sums
        atomicAdd(&ls[2 * 56 + 4 * v + 0], s10);
        atomicAdd(&ls[2 * 56 + 4 * v + 1], s11);
        atomicAdd(&ls[2 * 56 + 4 * v + 2], s12);
        atomicAdd(&ls[2 * 56 + 4 * v + 3], s13);
        atomicAdd(&ls[3 * 56 + 4 * v + 0], s20);
        atomicAdd(&ls[3 * 56 + 4 * v + 1], s21);
        atomicAdd(&ls[3 * 56 + 4 * v + 2], s22);
        atomicAdd(&ls[3 * 56 + 4 * v + 3], s23);
    }
    __syncthreads();

    if (tid < 224) ws[(size_t)blockIdx.x * 224 + tid] = ls[tid];
}

__global__ __launch_bounds__(1024) void loc_finalize(const float* __restrict__ ws,
                                                     float* __restrict__ out) {
    __shared__ float sums[7168];  // [t][arr][56] = 28 KB
    const int tid = threadIdx.x;

    // Phase 1: reduce the 16 d-group partials (coalesced; 7 outputs/thread).
    #pragma unroll
    for (int k = 0; k < 7; ++k) {
        const int o = tid + 1024 * k;       // o = (t*4 + arr)*56 + i
        const int t = o / 224;
        const int r = o % 224;
        float a = 0.f;
        #pragma unroll
        for (int dg = 0; dg < 16; ++dg) a += ws[(size_t)(t * 16 + dg) * 224 + r];
        sums[o] = a;
    }
    __syncthreads();

    // Phase 2: 64 threads = (t 0..31) x (H-axis / W-axis); serial 56-elem scans.
    if (tid < 64) {
        const int t    = tid & 31;
        const bool isW = tid >= 32;

        const float* s1 = &sums[(t * 4 + (isW ? 2 : 0)) * 56];
        const float* s2 = &sums[(t * 4 + (isW ? 3 : 1)) * 56];
        float* osuf = out + 1 + (isW ? 3584 : 0)    + t * 56;  // ga1 / ga3
        float* opre = out + 1 + (isW ? 5376 : 1792) + t * 56;  // ga2 / ga4

        const float n_per = 14336.f;  // D*W == D*H
        float part = 0.f;

        float a1 = 0.f, a2 = 0.f;
        for (int i = 55; i >= 0; --i) {            // suffix
            a1 += s1[i]; a2 += s2[i];
            const float n  = n_per * (float)(56 - i);
            const float ga = sqrtf(a2 + 2.0f * EPS * a1 + (EPS * EPS) * n);
            osuf[i] = log10f(ga);
            part += ga + EPS;
        }
        a1 = 0.f; a2 = 0.f;
        for (int i = 0; i < 56; ++i) {             // prefix
            a1 += s1[i]; a2 += s2[i];
            const float n  = n_per * (float)(i + 1);
            const float ga = sqrtf(a2 + 2.0f * EPS * a1 + (EPS * EPS) * n);
            opre[i] = log10f(ga);
            part += ga + EPS;
        }

        #pragma unroll
        for (int off = 32; off; off >>= 1) part += __shfl_down(part, off);
        if (tid == 0) out[0] = part * (1.0f / 128.0f);  // /T /4
    }
}

extern "C" void kernel_launch(void* const* d_in, const int* in_sizes, int n_in,
                              void* d_out, int out_size, void* d_ws, size_t ws_size,
                              hipStream_t stream) {
    const float* f = (const float*)d_in[0];
    float* out = (float*)d_out;
    float* ws  = (float*)d_ws;

    loc_reduce<<<dim3(512), dim3(832), 0, stream>>>(f, ws);
    loc_finalize<<<dim3(1), dim3(1024), 0, stream>>>(ws, out);
}